// Round 6
// baseline (1371.540 us; speedup 1.0000x reference)
//
#include <hip/hip_runtime.h>
#include <cstdint>
#include <cstddef>

#define M_ROWS 65536
#define N_COLS 1024
#define K_DIM  1024

typedef _Float16 f16x8 __attribute__((ext_vector_type(8)));
typedef float f32x4 __attribute__((ext_vector_type(4)));

// ---------------- prep: scale/bias ----------------
__global__ __launch_bounds__(256) void prep_scale_bias(
    const float* __restrict__ gamma, const float* __restrict__ beta,
    const float* __restrict__ mean, const float* __restrict__ var,
    float* __restrict__ bias, float* __restrict__ scale)
{
  int i = blockIdx.x * 256 + threadIdx.x;
  if (i < N_COLS) {
    float s = gamma[i] * rsqrtf(var[i] + 1e-3f);
    scale[i] = s;
    bias[i] = beta[i] - mean[i] * s;
  }
}

// ---------------- prep: W -> Bp (transposed, scaled, f16, fragment-permuted) ----------------
// Bp chunk layout: 16B chunk index = ((kt*16 + wn)*64 + lane)*8 + kc*4 + fn
// holding Wt[n = wn*64 + fn*16 + li][k = kt*64 + kc*32 + g*8 .. +8], lane = g*16+li.
// => in the GEMM, lane's 16 fragments for one kt are contiguous 128B at Bp + tid*128 + kt*131072.
__global__ __launch_bounds__(256) void prep_bp(
    const float* __restrict__ W, const float* __restrict__ scale,
    char* __restrict__ Bp)
{
  __shared__ float tile[64][68];
  int k0 = blockIdx.x * 64, n0 = blockIdx.y * 64;
  int t = threadIdx.x;
  int kr = t >> 2, q = t & 3;
  #pragma unroll
  for (int j = 0; j < 4; ++j) {
    float4 v = *(const float4*)(W + (size_t)(k0 + kr) * N_COLS + n0 + q * 16 + j * 4);
    *(float4*)(&tile[kr][q * 16 + j * 4]) = v;
  }
  __syncthreads();
  int nr = t >> 2;
  int n = n0 + nr;
  float sn = scale[n];
  __align__(16) _Float16 h[16];
  #pragma unroll
  for (int j = 0; j < 16; ++j)
    h[j] = (_Float16)(tile[q * 16 + j][nr] * sn);   // h[j] = Wt[n][k0+q*16+j]
  int wn = n >> 6, fn = (n >> 4) & 3, li = n & 15;
  #pragma unroll
  for (int c = 0; c < 2; ++c) {
    int k = k0 + q * 16 + c * 8;
    int kidx = k >> 3;
    int g = kidx & 3, kc = (kidx >> 2) & 1, kt = kidx >> 3;
    int lane = g * 16 + li;
    size_t chunk = ((size_t)(kt * 16 + wn) * 64 + lane) * 8 + kc * 4 + fn;
    *(uint4*)(Bp + chunk * 16) = *(const uint4*)(&h[c * 8]);
  }
}

// ---------------- fused: z = (A @ W~ + bias) * priors ; out = sparsemax(z) ----------------
// 1024 threads = 16 waves; block = 32 rows x 1024 cols. Wave wn owns 64-col band.
// amdgpu_waves_per_eu(4,4): allocator targets 4 waves/EU -> up to 128 VGPR, no spill.
// K-loop: ZERO barriers, no LDS. A fp32 fragments straight from global (L1/L2-shared
// across the block's waves), cvt to f16 in-register. B from L2-resident permuted Bp,
// one base address per lane, immediate offsets.
__global__ __launch_bounds__(1024) __attribute__((amdgpu_waves_per_eu(4, 4)))
void fused_gemm_sparsemax(
    const float* __restrict__ A, const char* __restrict__ Bp,
    const float* __restrict__ bias, const float* __restrict__ priors,
    float* __restrict__ out)
{
  __shared__ float pr[32][18];           // per-row per-wave partials (padded)
  __shared__ float prk[32][18];          // support-count partials (Newton)
  __shared__ float tot[32];
  __shared__ float totk[32];

  const int tid = threadIdx.x;
  const int lane = tid & 63, wn = tid >> 6;
  const int li = lane & 15, g = lane >> 4;
  const int m0 = blockIdx.x * 32;

  f32x4 acc[2][4];
  #pragma unroll
  for (int fm = 0; fm < 2; ++fm)
    #pragma unroll
    for (int fn = 0; fn < 4; ++fn) acc[fm][fn] = (f32x4){0.f, 0.f, 0.f, 0.f};

  // ---- per-lane A row pointers (fragment rows li and 16+li) ----
  const float* a0p = A + (size_t)(m0 + li) * K_DIM + g * 8;
  const float* a1p = A + (size_t)(m0 + 16 + li) * K_DIM + g * 8;
  // ---- B base: one address per lane, contiguous 128B per kt ----
  const char* bkt = Bp + (size_t)tid * 128;

  for (int kt = 0; kt < 16; ++kt) {
    // all 8 B-fragment loads for this kt (immediate offsets, L2-resident)
    f16x8 bf[2][4];
    #pragma unroll
    for (int kc = 0; kc < 2; ++kc)
      #pragma unroll
      for (int fn = 0; fn < 4; ++fn)
        bf[kc][fn] = *(const f16x8*)(bkt + kc * 64 + fn * 16);
    bkt += 131072;

    #pragma unroll
    for (int kc = 0; kc < 2; ++kc) {
      // A fragments: 8 fp32 each, contiguous 32B, cvt to f16 in-reg
      float4 x0 = *(const float4*)(a0p + kc * 32);
      float4 x1 = *(const float4*)(a0p + kc * 32 + 4);
      float4 y0 = *(const float4*)(a1p + kc * 32);
      float4 y1 = *(const float4*)(a1p + kc * 32 + 4);
      f16x8 af0 = {(_Float16)x0.x, (_Float16)x0.y, (_Float16)x0.z, (_Float16)x0.w,
                   (_Float16)x1.x, (_Float16)x1.y, (_Float16)x1.z, (_Float16)x1.w};
      f16x8 af1 = {(_Float16)y0.x, (_Float16)y0.y, (_Float16)y0.z, (_Float16)y0.w,
                   (_Float16)y1.x, (_Float16)y1.y, (_Float16)y1.z, (_Float16)y1.w};
      #pragma unroll
      for (int fn = 0; fn < 4; ++fn) {
        acc[0][fn] = __builtin_amdgcn_mfma_f32_16x16x32_f16(af0, bf[kc][fn], acc[0][fn], 0, 0, 0);
        acc[1][fn] = __builtin_amdgcn_mfma_f32_16x16x32_f16(af1, bf[kc][fn], acc[1][fn], 0, 0, 0);
      }
    }
    a0p += 64;
    a1p += 64;
  }

  // ---- epilogue: z = (acc + bias) * priors, in registers ----
  {
    float bv[4];
    #pragma unroll
    for (int fn = 0; fn < 4; ++fn) bv[fn] = bias[wn * 64 + fn * 16 + li];
    #pragma unroll
    for (int fm = 0; fm < 2; ++fm)
      #pragma unroll
      for (int r = 0; r < 4; ++r) {
        const float* pp = priors + (size_t)(m0 + fm * 16 + g * 4 + r) * N_COLS + wn * 64 + li;
        #pragma unroll
        for (int fn = 0; fn < 4; ++fn)
          acc[fm][fn][r] = (acc[fm][fn][r] + bv[fn]) * pp[fn * 16];
      }
  }

  // ---- stage 1: row max (shfl over li-groups, two-level LDS combine) ----
  float lo[2][4], hi[2][4];
  {
    float mx[2][4];
    #pragma unroll
    for (int fm = 0; fm < 2; ++fm)
      #pragma unroll
      for (int r = 0; r < 4; ++r) {
        float m = acc[fm][0][r];
        #pragma unroll
        for (int fn = 1; fn < 4; ++fn) m = fmaxf(m, acc[fm][fn][r]);
        m = fmaxf(m, __shfl_xor(m, 1, 64));
        m = fmaxf(m, __shfl_xor(m, 2, 64));
        m = fmaxf(m, __shfl_xor(m, 4, 64));
        m = fmaxf(m, __shfl_xor(m, 8, 64));
        mx[fm][r] = m;
      }
    if (li == 0) {
      #pragma unroll
      for (int fm = 0; fm < 2; ++fm)
        #pragma unroll
        for (int r = 0; r < 4; ++r)
          pr[fm * 16 + g * 4 + r][wn] = mx[fm][r];
    }
    __syncthreads();
    if (wn < 4) {
      int row = wn * 8 + (lane >> 3);
      float2 p2 = *(const float2*)(&pr[row][2 * (lane & 7)]);
      float m = fmaxf(p2.x, p2.y);
      m = fmaxf(m, __shfl_xor(m, 1, 64));
      m = fmaxf(m, __shfl_xor(m, 2, 64));
      m = fmaxf(m, __shfl_xor(m, 4, 64));
      if ((lane & 7) == 0) tot[row] = m;
    }
    __syncthreads();
    #pragma unroll
    for (int fm = 0; fm < 2; ++fm)
      #pragma unroll
      for (int r = 0; r < 4; ++r) {
        float M = tot[fm * 16 + g * 4 + r];
        lo[fm][r] = M - 1.0f;
        hi[fm][r] = M;
      }
  }

  // ---- stage 2: 12 bisections on f(tau) = sum relu(z - tau) - 1 ----
  for (int it = 0; it < 12; ++it) {
    float tt[2][4], sv[2][4];
    #pragma unroll
    for (int fm = 0; fm < 2; ++fm)
      #pragma unroll
      for (int r = 0; r < 4; ++r) {
        float t = 0.5f * (lo[fm][r] + hi[fm][r]);
        tt[fm][r] = t;
        float s = 0.f;
        #pragma unroll
        for (int fn = 0; fn < 4; ++fn) s += fmaxf(acc[fm][fn][r] - t, 0.f);
        s += __shfl_xor(s, 1, 64);
        s += __shfl_xor(s, 2, 64);
        s += __shfl_xor(s, 4, 64);
        s += __shfl_xor(s, 8, 64);
        sv[fm][r] = s;
      }
    if (li == 0) {
      #pragma unroll
      for (int fm = 0; fm < 2; ++fm)
        #pragma unroll
        for (int r = 0; r < 4; ++r)
          pr[fm * 16 + g * 4 + r][wn] = sv[fm][r];
    }
    __syncthreads();
    if (wn < 4) {
      int row = wn * 8 + (lane >> 3);
      float2 p2 = *(const float2*)(&pr[row][2 * (lane & 7)]);
      float s = p2.x + p2.y;
      s += __shfl_xor(s, 1, 64);
      s += __shfl_xor(s, 2, 64);
      s += __shfl_xor(s, 4, 64);
      if ((lane & 7) == 0) tot[row] = s;
    }
    __syncthreads();
    #pragma unroll
    for (int fm = 0; fm < 2; ++fm)
      #pragma unroll
      for (int r = 0; r < 4; ++r) {
        if (tot[fm * 16 + g * 4 + r] >= 1.f) lo[fm][r] = tt[fm][r];
        else hi[fm][r] = tt[fm][r];
      }
  }

  // ---- stage 3: 2 exact Newton polish steps: tau = (sum_{z>tau} z - 1) / k ----
  float tv[2][4];
  #pragma unroll
  for (int fm = 0; fm < 2; ++fm)
    #pragma unroll
    for (int r = 0; r < 4; ++r) tv[fm][r] = lo[fm][r];

  for (int nit = 0; nit < 2; ++nit) {
    float sv[2][4], kv[2][4];
    #pragma unroll
    for (int fm = 0; fm < 2; ++fm)
      #pragma unroll
      for (int r = 0; r < 4; ++r) {
        float s = 0.f, k = 0.f;
        float t = tv[fm][r];
        #pragma unroll
        for (int fn = 0; fn < 4; ++fn) {
          float d = acc[fm][fn][r];
          bool gt = d > t;
          s += gt ? d : 0.f;
          k += gt ? 1.f : 0.f;
        }
        s += __shfl_xor(s, 1, 64); k += __shfl_xor(k, 1, 64);
        s += __shfl_xor(s, 2, 64); k += __shfl_xor(k, 2, 64);
        s += __shfl_xor(s, 4, 64); k += __shfl_xor(k, 4, 64);
        s += __shfl_xor(s, 8, 64); k += __shfl_xor(k, 8, 64);
        sv[fm][r] = s; kv[fm][r] = k;
      }
    if (li == 0) {
      #pragma unroll
      for (int fm = 0; fm < 2; ++fm)
        #pragma unroll
        for (int r = 0; r < 4; ++r) {
          pr[fm * 16 + g * 4 + r][wn] = sv[fm][r];
          prk[fm * 16 + g * 4 + r][wn] = kv[fm][r];
        }
    }
    __syncthreads();
    if (wn < 4) {
      int row = wn * 8 + (lane >> 3);
      float2 p2 = *(const float2*)(&pr[row][2 * (lane & 7)]);
      float2 q2 = *(const float2*)(&prk[row][2 * (lane & 7)]);
      float s = p2.x + p2.y;
      float k = q2.x + q2.y;
      s += __shfl_xor(s, 1, 64); k += __shfl_xor(k, 1, 64);
      s += __shfl_xor(s, 2, 64); k += __shfl_xor(k, 2, 64);
      s += __shfl_xor(s, 4, 64); k += __shfl_xor(k, 4, 64);
      if ((lane & 7) == 0) { tot[row] = s; totk[row] = k; }
    }
    __syncthreads();
    #pragma unroll
    for (int fm = 0; fm < 2; ++fm)
      #pragma unroll
      for (int r = 0; r < 4; ++r) {
        int row = fm * 16 + g * 4 + r;
        tv[fm][r] = (tot[row] - 1.f) / totk[row];   // k >= 1 (row max stays in support)
      }
  }

  // ---- write out = relu(z - tau) ----
  #pragma unroll
  for (int fm = 0; fm < 2; ++fm)
    #pragma unroll
    for (int r = 0; r < 4; ++r) {
      float* op = out + (size_t)(m0 + fm * 16 + g * 4 + r) * N_COLS + wn * 64 + li;
      float t = tv[fm][r];
      #pragma unroll
      for (int fn = 0; fn < 4; ++fn)
        op[fn * 16] = fmaxf(acc[fm][fn][r] - t, 0.f);
    }
}

// ---------------- launch ----------------
extern "C" void kernel_launch(void* const* d_in, const int* in_sizes, int n_in,
                              void* d_out, int out_size, void* d_ws, size_t ws_size,
                              hipStream_t stream) {
  const float* inputs = (const float*)d_in[0];
  const float* priors = (const float*)d_in[1];
  const float* W      = (const float*)d_in[2];
  const float* gamma  = (const float*)d_in[3];
  const float* beta   = (const float*)d_in[4];
  const float* mean   = (const float*)d_in[5];
  const float* var    = (const float*)d_in[6];
  float* out = (float*)d_out;

  char* ws = (char*)d_ws;
  float* bias  = (float*)ws;                 // 4 KB
  float* scale = (float*)(ws + 4096);        // 4 KB
  char*  Bp    = ws + 8192;                  // 2 MB, fragment-permuted scaled W^T (f16)

  prep_scale_bias<<<4, 256, 0, stream>>>(gamma, beta, mean, var, bias, scale);
  prep_bp<<<dim3(16, 16), 256, 0, stream>>>(W, scale, Bp);
  fused_gemm_sparsemax<<<M_ROWS / 32, 1024, 0, stream>>>(inputs, Bp, bias, priors, out);
}

// Round 7
// 472.565 us; speedup vs baseline: 2.9023x; 2.9023x over previous
//
#include <hip/hip_runtime.h>
#include <cstdint>
#include <cstddef>

#define M_ROWS 65536
#define N_COLS 1024
#define K_DIM  1024

typedef _Float16 f16x8 __attribute__((ext_vector_type(8)));
typedef float f32x4 __attribute__((ext_vector_type(4)));

// ---------------- prep: scale/bias ----------------
__global__ __launch_bounds__(256) void prep_scale_bias(
    const float* __restrict__ gamma, const float* __restrict__ beta,
    const float* __restrict__ mean, const float* __restrict__ var,
    float* __restrict__ bias, float* __restrict__ scale)
{
  int i = blockIdx.x * 256 + threadIdx.x;
  if (i < N_COLS) {
    float s = gamma[i] * rsqrtf(var[i] + 1e-3f);
    scale[i] = s;
    bias[i] = beta[i] - mean[i] * s;
  }
}

// ---------------- prep: W -> Wt (transposed, scaled, f16) ----------------
__global__ __launch_bounds__(256) void prep_wt(
    const float* __restrict__ W, const float* __restrict__ scale,
    _Float16* __restrict__ Wt)
{
  __shared__ float tile[64][68];
  int k0 = blockIdx.x * 64, n0 = blockIdx.y * 64;
  int t = threadIdx.x;
  int kr = t >> 2, q = t & 3;
  #pragma unroll
  for (int j = 0; j < 4; ++j) {
    float4 v = *(const float4*)(W + (size_t)(k0 + kr) * N_COLS + n0 + q * 16 + j * 4);
    *(float4*)(&tile[kr][q * 16 + j * 4]) = v;
  }
  __syncthreads();
  int nr = t >> 2;
  float sn = scale[n0 + nr];
  __align__(16) _Float16 h[16];
  #pragma unroll
  for (int j = 0; j < 16; ++j)
    h[j] = (_Float16)(tile[q * 16 + j][nr] * sn);
  uint4* dst = (uint4*)(Wt + (size_t)(n0 + nr) * K_DIM + k0 + q * 16);
  dst[0] = *(uint4*)(&h[0]);
  dst[1] = *(uint4*)(&h[8]);
}

// ---------------- prep: A (fp32) -> Af (f16), grid-stride, vectorized ----------------
__global__ __launch_bounds__(256) void conv_a_f16(
    const float* __restrict__ A, _Float16* __restrict__ Af)
{
  const size_t total8 = (size_t)M_ROWS * K_DIM / 8;
  size_t i = (size_t)blockIdx.x * 256 + threadIdx.x;
  const size_t stride = (size_t)gridDim.x * 256;
  for (; i < total8; i += stride) {
    float4 a = *(const float4*)(A + i * 8);
    float4 b = *(const float4*)(A + i * 8 + 4);
    union { _Float16 h[8]; uint4 u; } p;
    p.h[0] = (_Float16)a.x; p.h[1] = (_Float16)a.y;
    p.h[2] = (_Float16)a.z; p.h[3] = (_Float16)a.w;
    p.h[4] = (_Float16)b.x; p.h[5] = (_Float16)b.y;
    p.h[6] = (_Float16)b.z; p.h[7] = (_Float16)b.w;
    *(uint4*)(Af + i * 8) = p.u;
  }
}

// ---------------- GEMM: single-buffered LDS (32KB) -> 5 blocks/CU ----------------
// m97-style 2-barrier K-step: {issue gload_lds A+B; barrier (vmcnt drain); 32 MFMA; barrier}.
// Latency hidden by cross-block wave overlap (5 blocks/CU at 32KB LDS, VGPR ~88).
__global__ __launch_bounds__(256, 2) void gemm_f16_sb(
    const _Float16* __restrict__ Af, const _Float16* __restrict__ Wt,
    const float* __restrict__ bias, const float* __restrict__ priors,
    float* __restrict__ out)
{
  __shared__ char smem[32768];  // A @0 (16KB), B @16384 (16KB)
  const int tid = threadIdx.x;
  const int lane = tid & 63, wid = tid >> 6;
  const int wm = wid >> 1, wn = wid & 1;

  // bijective XCD swizzle (nwg=4096, 4096%8==0)
  int orig = blockIdx.x;
  int wgid = (orig & 7) * 512 + (orig >> 3);
  int mb = wgid >> 3, nb = wgid & 7;
  const int m0 = mb * 128, n0 = nb * 128;

  f32x4 acc[4][4];
  #pragma unroll
  for (int i = 0; i < 4; ++i)
    #pragma unroll
    for (int j = 0; j < 4; ++j) acc[i][j] = (f32x4){0.f, 0.f, 0.f, 0.f};

  // stage one 128x64 f16 tile (16KB) — linear LDS dest, inverse-swizzled global src (rule 21)
  auto issueTile = [&](const _Float16* base, int rowBase, int kt, int ldsOff) {
    #pragma unroll
    for (int t4 = 0; t4 < 4; ++t4) {
      int ch = t4 * 256 + tid;     // 16B chunk index, 1024 chunks
      int rl = ch >> 3, c = ch & 7;
      const char* src = (const char*)base
          + ((size_t)(rowBase + rl) * K_DIM + kt * 64) * 2
          + ((c * 16) ^ ((rl & 7) << 4));
      __builtin_amdgcn_global_load_lds(
          (const __attribute__((address_space(1))) unsigned int*)src,
          (__attribute__((address_space(3))) unsigned int*)(&smem[ldsOff + ch * 16]),
          16, 0, 0);
    }
  };

  for (int kt = 0; kt < 16; ++kt) {
    issueTile(Af, m0, kt, 0);
    issueTile(Wt, n0, kt, 16384);
    __syncthreads();               // drains vmcnt -> tiles visible
    #pragma unroll
    for (int kc = 0; kc < 2; ++kc) {
      int k2 = (kc * 32 + ((lane >> 4) * 8)) * 2;
      f16x8 af[4], bf[4];
      #pragma unroll
      for (int fm = 0; fm < 4; ++fm) {
        int rl = wm * 64 + fm * 16 + (lane & 15);
        af[fm] = *(const f16x8*)(&smem[rl * 128 + (k2 ^ ((rl & 7) << 4))]);
      }
      #pragma unroll
      for (int fn = 0; fn < 4; ++fn) {
        int nl = wn * 64 + fn * 16 + (lane & 15);
        bf[fn] = *(const f16x8*)(&smem[16384 + nl * 128 + (k2 ^ ((nl & 7) << 4))]);
      }
      #pragma unroll
      for (int fm = 0; fm < 4; ++fm)
        #pragma unroll
        for (int fn = 0; fn < 4; ++fn)
          acc[fm][fn] = __builtin_amdgcn_mfma_f32_16x16x32_f16(af[fm], bf[fn], acc[fm][fn], 0, 0, 0);
    }
    __syncthreads();               // all reads done before next kt's loads overwrite
  }

  // epilogue: + bias, * priors, write z
  #pragma unroll
  for (int fn = 0; fn < 4; ++fn) {
    int col = n0 + wn * 64 + fn * 16 + (lane & 15);
    float bv = bias[col];
    #pragma unroll
    for (int fm = 0; fm < 4; ++fm) {
      int row0 = m0 + wm * 64 + fm * 16 + ((lane >> 4) << 2);
      #pragma unroll
      for (int r = 0; r < 4; ++r) {
        size_t idx = (size_t)(row0 + r) * N_COLS + col;
        out[idx] = (acc[fm][fn][r] + bv) * priors[idx];
      }
    }
  }
}

// ---------------- FALLBACK GEMM (ws too small): A reg-staged fp32->f16, dbuf ----------------
__global__ __launch_bounds__(256, 2) void gemm_f16(
    const float* __restrict__ A, const _Float16* __restrict__ Wt,
    const float* __restrict__ bias, const float* __restrict__ priors,
    float* __restrict__ out)
{
  __shared__ char smem[65536];
  const int tid = threadIdx.x;
  const int lane = tid & 63, wid = tid >> 6;
  const int wm = wid >> 1, wn = wid & 1;

  int orig = blockIdx.x;
  int wgid = (orig & 7) * 512 + (orig >> 3);
  int mb = wgid >> 3, nb = wgid & 7;
  const int m0 = mb * 128, n0 = nb * 128;

  f32x4 acc[4][4];
  #pragma unroll
  for (int i = 0; i < 4; ++i)
    #pragma unroll
    for (int j = 0; j < 4; ++j) acc[i][j] = (f32x4){0.f, 0.f, 0.f, 0.f};

  float4 areg[8];

  auto loadA = [&](int kt) {
    #pragma unroll
    for (int j = 0; j < 8; ++j) {
      int f = j * 256 + tid;
      int ml = f >> 4;
      int k4 = (f & 15) << 2;
      areg[j] = *(const float4*)(A + (size_t)(m0 + ml) * K_DIM + kt * 64 + k4);
    }
  };
  auto storeA = [&](int buf) {
    int base = buf * 16384;
    #pragma unroll
    for (int j = 0; j < 8; ++j) {
      int f = j * 256 + tid;
      int ml = f >> 4;
      int k4 = (f & 15) << 2;
      int off = ml * 128 + ((k4 * 2) ^ ((ml & 7) << 4));
      union { _Float16 h[4]; uint2 u; } p;
      p.h[0] = (_Float16)areg[j].x;
      p.h[1] = (_Float16)areg[j].y;
      p.h[2] = (_Float16)areg[j].z;
      p.h[3] = (_Float16)areg[j].w;
      *(uint2*)(&smem[base + off]) = p.u;
    }
  };
  auto issueB = [&](int kt, int buf) {
    int base = 32768 + buf * 16384;
    #pragma unroll
    for (int t4 = 0; t4 < 4; ++t4) {
      int ch = t4 * 256 + tid;
      int nl = ch >> 3, c = ch & 7;
      const char* src = (const char*)Wt
          + ((size_t)(n0 + nl) * K_DIM + kt * 64) * 2
          + ((c * 16) ^ ((nl & 7) << 4));
      __builtin_amdgcn_global_load_lds(
          (const __attribute__((address_space(1))) unsigned int*)src,
          (__attribute__((address_space(3))) unsigned int*)(&smem[base + ch * 16]),
          16, 0, 0);
    }
  };

  loadA(0);
  issueB(0, 0);
  storeA(0);
  __syncthreads();

  for (int kt = 0; kt < 16; ++kt) {
    int cur = kt & 1, nxt = cur ^ 1;
    if (kt < 15) {
      loadA(kt + 1);
      issueB(kt + 1, nxt);
    }
    int ab = cur * 16384, bb = 32768 + cur * 16384;
    #pragma unroll
    for (int kc = 0; kc < 2; ++kc) {
      int k2 = (kc * 32 + ((lane >> 4) * 8)) * 2;
      f16x8 af[4], bf[4];
      #pragma unroll
      for (int fm = 0; fm < 4; ++fm) {
        int rl = wm * 64 + fm * 16 + (lane & 15);
        af[fm] = *(const f16x8*)(&smem[ab + rl * 128 + (k2 ^ ((rl & 7) << 4))]);
      }
      #pragma unroll
      for (int fn = 0; fn < 4; ++fn) {
        int nl = wn * 64 + fn * 16 + (lane & 15);
        bf[fn] = *(const f16x8*)(&smem[bb + nl * 128 + (k2 ^ ((nl & 7) << 4))]);
      }
      #pragma unroll
      for (int fm = 0; fm < 4; ++fm)
        #pragma unroll
        for (int fn = 0; fn < 4; ++fn)
          acc[fm][fn] = __builtin_amdgcn_mfma_f32_16x16x32_f16(af[fm], bf[fn], acc[fm][fn], 0, 0, 0);
    }
    if (kt < 15) storeA(nxt);
    __syncthreads();
  }

  #pragma unroll
  for (int fn = 0; fn < 4; ++fn) {
    int col = n0 + wn * 64 + fn * 16 + (lane & 15);
    float bv = bias[col];
    #pragma unroll
    for (int fm = 0; fm < 4; ++fm) {
      int row0 = m0 + wm * 64 + fm * 16 + ((lane >> 4) << 2);
      #pragma unroll
      for (int r = 0; r < 4; ++r) {
        size_t idx = (size_t)(row0 + r) * N_COLS + col;
        out[idx] = (acc[fm][fn][r] + bv) * priors[idx];
      }
    }
  }
}

// ---------------- sparsemax, in place on d_out, one wave per row ----------------
__global__ __launch_bounds__(256) void sparsemax_rows(float* __restrict__ z)
{
  const int lane = threadIdx.x & 63, wid = threadIdx.x >> 6;
  const size_t row = (size_t)blockIdx.x * 4 + wid;
  float* p = z + row * N_COLS;

  float v[16];
  #pragma unroll
  for (int j = 0; j < 4; ++j) {
    float4 t = *(const float4*)(p + j * 256 + lane * 4);
    v[j * 4 + 0] = t.x; v[j * 4 + 1] = t.y; v[j * 4 + 2] = t.z; v[j * 4 + 3] = t.w;
  }

  float mx = v[0];
  #pragma unroll
  for (int j = 1; j < 16; ++j) mx = fmaxf(mx, v[j]);
  #pragma unroll
  for (int m = 1; m <= 32; m <<= 1) mx = fmaxf(mx, __shfl_xor(mx, m, 64));

  float lo = mx - 1.0f, hi = mx;
  for (int it = 0; it < 12; ++it) {
    float tau = 0.5f * (lo + hi);
    float s = 0.f;
    #pragma unroll
    for (int j = 0; j < 16; ++j) s += fmaxf(v[j] - tau, 0.f);
    #pragma unroll
    for (int m = 1; m <= 32; m <<= 1) s += __shfl_xor(s, m, 64);
    if (s >= 1.f) lo = tau; else hi = tau;
  }
  float tau = lo;
  #pragma unroll
  for (int it = 0; it < 2; ++it) {
    float s = 0.f, k = 0.f;
    #pragma unroll
    for (int j = 0; j < 16; ++j) {
      bool g = v[j] > tau;
      s += g ? v[j] : 0.f;
      k += g ? 1.f : 0.f;
    }
    #pragma unroll
    for (int m = 1; m <= 32; m <<= 1) { s += __shfl_xor(s, m, 64); k += __shfl_xor(k, m, 64); }
    tau = (s - 1.f) / k;
  }

  #pragma unroll
  for (int j = 0; j < 4; ++j) {
    float4 t;
    t.x = fmaxf(v[j * 4 + 0] - tau, 0.f);
    t.y = fmaxf(v[j * 4 + 1] - tau, 0.f);
    t.z = fmaxf(v[j * 4 + 2] - tau, 0.f);
    t.w = fmaxf(v[j * 4 + 3] - tau, 0.f);
    *(float4*)(p + j * 256 + lane * 4) = t;
  }
}

// ---------------- launch ----------------
extern "C" void kernel_launch(void* const* d_in, const int* in_sizes, int n_in,
                              void* d_out, int out_size, void* d_ws, size_t ws_size,
                              hipStream_t stream) {
  const float* inputs = (const float*)d_in[0];
  const float* priors = (const float*)d_in[1];
  const float* W      = (const float*)d_in[2];
  const float* gamma  = (const float*)d_in[3];
  const float* beta   = (const float*)d_in[4];
  const float* mean   = (const float*)d_in[5];
  const float* var    = (const float*)d_in[6];
  float* out = (float*)d_out;

  char* ws = (char*)d_ws;
  float* bias  = (float*)ws;                 // 4 KB
  float* scale = (float*)(ws + 4096);        // 4 KB
  _Float16* Wt = (_Float16*)(ws + 8192);     // 2 MB, [N][K] transposed+scaled
  const size_t AF_OFF = 8192 + (size_t)N_COLS * K_DIM * 2;   // 2105344
  _Float16* Af = (_Float16*)(ws + AF_OFF);   // 134 MB, [M][K] f16
  const size_t need = AF_OFF + (size_t)M_ROWS * K_DIM * 2;

  prep_scale_bias<<<4, 256, 0, stream>>>(gamma, beta, mean, var, bias, scale);
  prep_wt<<<dim3(16, 16), 256, 0, stream>>>(W, scale, Wt);

  if (ws_size >= need) {
    conv_a_f16<<<2048, 256, 0, stream>>>(inputs, Af);
    gemm_f16_sb<<<4096, 256, 0, stream>>>(Af, Wt, bias, priors, out);
  } else {
    gemm_f16<<<4096, 256, 0, stream>>>(inputs, Wt, bias, priors, out);
  }
  sparsemax_rows<<<16384, 256, 0, stream>>>(out);
}